// Round 8
// baseline (361.354 us; speedup 1.0000x reference)
//
#include <hip/hip_runtime.h>
#include <math.h>
#include <float.h>

#define B_ 2
#define S_ 2048
#define D_ 1024
#define H_ 16
#define V_ 4096
#define NZ_ 10
#define BS_ (B_ * S_)     // 4096 rows

typedef __attribute__((ext_vector_type(8))) __bf16 bf16x8;
typedef __attribute__((ext_vector_type(4))) float f32x4;
typedef unsigned long long ull;

#define MFMA16(a, b, c) __builtin_amdgcn_mfma_f32_16x16x32_bf16((a), (b), (c), 0, 0, 0)

__device__ __forceinline__ unsigned short f2bf(float f) {
  unsigned u = __builtin_bit_cast(unsigned, f);
  u = (u + 0x7FFFu + ((u >> 16) & 1u)) >> 16;
  return (unsigned short)u;
}
__device__ __forceinline__ float bf2f(unsigned short h) {
  unsigned u = ((unsigned)h) << 16;
  return __builtin_bit_cast(float, u);
}

// ---------------------------------------------------------------------------
// Fused prep: x hi/lo split | 4-weight split | omega bit-pack | Mband table.
// ---------------------------------------------------------------------------
__global__ __launch_bounds__(256) void prep_kernel(
    const float* __restrict__ x,
    const float* __restrict__ wq, const float* __restrict__ wk,
    const float* __restrict__ wv, const float* __restrict__ wo,
    const float* __restrict__ omega, const float* __restrict__ gamma,
    unsigned short* __restrict__ xh, unsigned short* __restrict__ xl,
    unsigned short* __restrict__ wqh, unsigned short* __restrict__ wql,
    unsigned short* __restrict__ wkh, unsigned short* __restrict__ wkl,
    unsigned short* __restrict__ wvh, unsigned short* __restrict__ woh,
    ull* __restrict__ obit, float* __restrict__ mbg) {
  const int bid = blockIdx.x;
  const int t = threadIdx.x;
  if (bid < 4096) {
    int i = (bid * 256 + t) * 4;
    float4 v = *(const float4*)(x + i);
    ushort4 h;
    h.x = f2bf(v.x); h.y = f2bf(v.y); h.z = f2bf(v.z); h.w = f2bf(v.w);
    *(ushort4*)(xh + i) = h;
    ushort4 l;
    l.x = f2bf(v.x - bf2f(h.x));
    l.y = f2bf(v.y - bf2f(h.y));
    l.z = f2bf(v.z - bf2f(h.z));
    l.w = f2bf(v.w - bf2f(h.w));
    *(ushort4*)(xl + i) = l;
  } else if (bid < 8192) {
    int idx = ((bid - 4096) * 256 + t) * 4;
    int w = idx >> 20;                      // D*D = 2^20
    int off = idx & ((1 << 20) - 1);
    const float* src; unsigned short* hi; unsigned short* lo;
    if (w == 0)      { src = wq; hi = wqh; lo = wql; }
    else if (w == 1) { src = wk; hi = wkh; lo = wkl; }
    else if (w == 2) { src = wv; hi = wvh; lo = nullptr; }
    else             { src = wo; hi = woh; lo = nullptr; }
    float4 v = *(const float4*)(src + off);
    ushort4 h;
    h.x = f2bf(v.x); h.y = f2bf(v.y); h.z = f2bf(v.z); h.w = f2bf(v.w);
    *(ushort4*)(hi + off) = h;
    if (lo) {
      ushort4 l;
      l.x = f2bf(v.x - bf2f(h.x));
      l.y = f2bf(v.y - bf2f(h.y));
      l.z = f2bf(v.z - bf2f(h.z));
      l.w = f2bf(v.w - bf2f(h.w));
      *(ushort4*)(lo + off) = l;
    }
  } else if (bid < 8192 + 65536) {
    int e = (bid - 8192) * 256 + t;
    bool ok = omega[e] != 0.f;
    ull mask = __ballot(ok);
    if ((t & 63) == 0) obit[e >> 6] = mask;
  } else {
    if (t < 64) {
      float delta = (float)t;
      float ld = logf(delta + 1.f);
      float cs = 0.f;
#pragma unroll
      for (int z = 0; z < NZ_; ++z) cs += cosf(gamma[z] * ld);
      mbg[t] = expf(-delta) * cs * 0.125f;
    }
  }
}

// ---------------------------------------------------------------------------
// maskbits: fmask[row][w] bit j = 1 iff (j <= i-64) && omega-unmasked;
// c0 = popcount; bm = near-band ballot.
// ---------------------------------------------------------------------------
__global__ __launch_bounds__(256) void maskbits_kernel(const int* __restrict__ ids,
                                                       const ull* __restrict__ obit,
                                                       ull* __restrict__ fmask,
                                                       int* __restrict__ c0,
                                                       ull* __restrict__ bm) {
  const int grow = blockIdx.x;
  const int b = grow >> 11, i = grow & 2047;
  const int t = threadIdx.x, lane = t & 63, wave = t >> 6;
  const int idi = ids[grow];
  const ull* orow = obit + ((size_t)idi << 6);
  __shared__ int cnt;
  if (t == 0) cnt = 0;
  if (t < 64) {
    int jj = i - t;
    bool ok = false;
    if (jj >= 0) {
      int idj = ids[b * S_ + jj];
      ok = (orow[idj >> 6] >> (idj & 63)) & 1ull;
    }
    ull mask = __ballot(ok);
    if (t == 0) bm[grow] = mask;
  }
  __syncthreads();
  const int jmax = i - 64;
  int pc = 0;
#pragma unroll
  for (int c = 0; c < 8; ++c) {
    int j = c * 256 + t;
    bool on = false;
    if (j <= jmax) {
      int idj = ids[b * S_ + j];
      on = (orow[idj >> 6] >> (idj & 63)) & 1ull;
    }
    ull mk = __ballot(on);
    if (lane == 0) {
      fmask[(size_t)grow * 32 + c * 4 + wave] = mk;
      pc += (int)__popcll(mk);
    }
  }
  if (lane == 0 && pc) atomicAdd(&cnt, pc);
  __syncthreads();
  if (t == 0) c0[grow] = cnt;
}

// ---------------------------------------------------------------------------
// Staging helper: NT tiles of [128 rows][32 cols] bf16, XOR-swizzled k-quads.
// ---------------------------------------------------------------------------
template <int NT>
__device__ __forceinline__ void stage_tiles(const unsigned short* const* gb,
                                            int wave, int lane, int K, int k0,
                                            unsigned short* dst) {
#pragma unroll
  for (int tile = 0; tile < NT; ++tile) {
#pragma unroll
    for (int half = 0; half < 2; ++half) {
      int c = wave + half * 4;
      int s = (c << 6) + lane;
      int row = s >> 2;
      int cq = (s & 3) ^ ((s >> 3) & 3);
      const unsigned short* g = gb[tile] + (size_t)row * K + k0 + (cq << 3);
      unsigned short* l = dst + tile * 4096 + (s << 3);
      __builtin_amdgcn_global_load_lds((const __attribute__((address_space(1))) void*)g,
                                       (__attribute__((address_space(3))) void*)l,
                                       16, 0, 0);
    }
  }
}

__device__ __forceinline__ void frag_loads(const unsigned short* tb, int base, int wsel,
                                           int m, int quad, bf16x8 (&f)[4]) {
#pragma unroll
  for (int i = 0; i < 4; ++i) {
    int r = wsel * 64 + i * 16 + m;
    f[i] = *(const bf16x8*)&tb[base + r * 32 + ((quad ^ ((r >> 1) & 3)) << 3)];
  }
}

__device__ __forceinline__ void qkv_compute(const unsigned short* tb, bool split,
                                            int wm, int wn, int m, int quad,
                                            f32x4 (&acc)[4][4]) {
  bf16x8 afh[4], bfh[4];
  frag_loads(tb, 0 * 4096, wm, m, quad, afh);
  frag_loads(tb, 1 * 4096, wn, m, quad, bfh);
  if (split) {
    bf16x8 afl[4], bfl[4];
    frag_loads(tb, 2 * 4096, wm, m, quad, afl);
    frag_loads(tb, 3 * 4096, wn, m, quad, bfl);
#pragma unroll
    for (int mt = 0; mt < 4; ++mt)
#pragma unroll
      for (int nt = 0; nt < 4; ++nt) {
        acc[mt][nt] = MFMA16(afh[mt], bfh[nt], acc[mt][nt]);
        acc[mt][nt] = MFMA16(afl[mt], bfh[nt], acc[mt][nt]);
        acc[mt][nt] = MFMA16(afh[mt], bfl[nt], acc[mt][nt]);
      }
  } else {
#pragma unroll
    for (int mt = 0; mt < 4; ++mt)
#pragma unroll
      for (int nt = 0; nt < 4; ++nt)
        acc[mt][nt] = MFMA16(afh[mt], bfh[nt], acc[mt][nt]);
  }
}

// ---------------------------------------------------------------------------
// Fused Q/K/V projection GEMM; V output written TRANSPOSED via LDS.
// ---------------------------------------------------------------------------
__global__ __launch_bounds__(256) void mfma_gemm_qkv(
    const unsigned short* __restrict__ xh, const unsigned short* __restrict__ xl,
    const unsigned short* __restrict__ wqh, const unsigned short* __restrict__ wql,
    const unsigned short* __restrict__ wkh, const unsigned short* __restrict__ wkl,
    const unsigned short* __restrict__ wvh,
    const float* __restrict__ bq, const float* __restrict__ bk,
    const float* __restrict__ bv,
    unsigned short* __restrict__ qoh, unsigned short* __restrict__ qol,
    unsigned short* __restrict__ koh, unsigned short* __restrict__ kol,
    unsigned short* __restrict__ vt) {
  __shared__ unsigned short tiles[2][4 * 4096];   // 64 KB
  const int t = threadIdx.x;
  const int wave = t >> 6, lane = t & 63;
  const int which = blockIdx.x >> 3;
  const int n0 = (blockIdx.x & 7) * 128;
  const int i0 = blockIdx.y * 128;
  const int K = D_, N = D_;
  const int wm = wave >> 1, wn = wave & 1;
  const int m = lane & 15, quad = lane >> 4;

  const unsigned short* Wh = (which == 0) ? wqh : (which == 1) ? wkh : wvh;
  const unsigned short* Wl = (which == 0) ? wql : wkl;
  const float* bias = (which == 0) ? bq : (which == 1) ? bk : bv;
  unsigned short* Chi = (which == 0) ? qoh : (which == 1) ? koh : vt;
  unsigned short* Clo = (which == 0) ? qol : (which == 1) ? kol : nullptr;
  const bool split = (which < 2);

  const unsigned short* gb[4];
  gb[0] = xh + (size_t)i0 * K;
  gb[1] = Wh + (size_t)n0 * K;
  gb[2] = xl + (size_t)i0 * K;
  gb[3] = Wl + (size_t)n0 * K;

  f32x4 acc[4][4] = {};

  if (split) stage_tiles<4>(gb, wave, lane, K, 0, tiles[0]);
  else       stage_tiles<2>(gb, wave, lane, K, 0, tiles[0]);
  __syncthreads();

  for (int k0 = 0; k0 < K; k0 += 64) {
    if (split) stage_tiles<4>(gb, wave, lane, K, k0 + 32, tiles[1]);
    else       stage_tiles<2>(gb, wave, lane, K, k0 + 32, tiles[1]);
    qkv_compute(tiles[0], split, wm, wn, m, quad, acc);
    __syncthreads();
    if (k0 + 64 < K) {
      if (split) stage_tiles<4>(gb, wave, lane, K, k0 + 64, tiles[0]);
      else       stage_tiles<2>(gb, wave, lane, K, k0 + 64, tiles[0]);
    }
    qkv_compute(tiles[1], split, wm, wn, m, quad, acc);
    __syncthreads();
  }

  float bvv[4];
#pragma unroll
  for (int nt = 0; nt < 4; ++nt) bvv[nt] = bias[n0 + wn * 64 + nt * 16 + m];

  if (which == 2) {
    unsigned short* E = &tiles[0][0];           // 128 x 132 = 16896 <= 32768
#pragma unroll
    for (int mt = 0; mt < 4; ++mt)
#pragma unroll
      for (int nt = 0; nt < 4; ++nt) {
        int lc = wn * 64 + nt * 16 + m;
#pragma unroll
        for (int r = 0; r < 4; ++r) {
          int lr = wm * 64 + mt * 16 + quad * 4 + r;
          E[lr * 132 + lc] = f2bf(acc[mt][nt][r] + bvv[nt]);
        }
      }
    __syncthreads();
    const int bq2 = i0 >> 11, il0 = i0 & 2047;
    for (int c = t; c < 4096; c += 256) {
      int lcol = c >> 5, i4 = (c & 31) << 2;
      ushort4 vv;
      vv.x = E[(i4 + 0) * 132 + lcol];
      vv.y = E[(i4 + 1) * 132 + lcol];
      vv.z = E[(i4 + 2) * 132 + lcol];
      vv.w = E[(i4 + 3) * 132 + lcol];
      *(ushort4*)(Chi + ((size_t)bq2 * D_ + n0 + lcol) * S_ + il0 + i4) = vv;
    }
  } else {
#pragma unroll
    for (int mt = 0; mt < 4; ++mt) {
      int rbase = i0 + wm * 64 + mt * 16 + quad * 4;
#pragma unroll
      for (int nt = 0; nt < 4; ++nt) {
        int col = n0 + wn * 64 + nt * 16 + m;
#pragma unroll
        for (int r = 0; r < 4; ++r) {
          float val = acc[mt][nt][r] + bvv[nt];
          size_t idx = (size_t)(rbase + r) * N + col;
          unsigned short hv = f2bf(val);
          Chi[idx] = hv;
          Clo[idx] = f2bf(val - bf2f(hv));
        }
      }
    }
  }
}

// ---------------------------------------------------------------------------
// Shared 64x128-tile GEMM machinery (A: 64 rows, B: 128 rows, K-step 32).
// LDS layout per buffer: A[2048] | B[4096] ushorts.
// ---------------------------------------------------------------------------
__device__ __forceinline__ void t64_stageA(const unsigned short* __restrict__ Ab,
                                           int wave, int lane, int strideA, int k0,
                                           unsigned short* dstA) {
  int s = (wave << 6) + lane;                 // 4 chunks, one per wave
  int row = s >> 2;
  int cq = (s & 3) ^ ((s >> 3) & 3);
  const unsigned short* g = Ab + (size_t)row * strideA + k0 + (cq << 3);
  __builtin_amdgcn_global_load_lds((const __attribute__((address_space(1))) void*)g,
                                   (__attribute__((address_space(3))) void*)(dstA + (s << 3)),
                                   16, 0, 0);
}

__device__ __forceinline__ void t64_stageB(const unsigned short* __restrict__ Bb,
                                           int wave, int lane, int strideB, int k0,
                                           unsigned short* dstB) {
#pragma unroll
  for (int half = 0; half < 2; ++half) {
    int c = wave + half * 4;
    int s = (c << 6) + lane;
    int row = s >> 2;
    int cq = (s & 3) ^ ((s >> 3) & 3);
    const unsigned short* g = Bb + (size_t)row * strideB + k0 + (cq << 3);
    __builtin_amdgcn_global_load_lds((const __attribute__((address_space(1))) void*)g,
                                     (__attribute__((address_space(3))) void*)(dstB + (s << 3)),
                                     16, 0, 0);
  }
}

__device__ __forceinline__ void t64_compute(const unsigned short* tb,
                                            int wm, int wn, int m, int quad,
                                            f32x4 (&acc)[2][4]) {
  bf16x8 af[2], bf[4];
#pragma unroll
  for (int i = 0; i < 2; ++i) {
    int r = wm * 32 + i * 16 + m;
    af[i] = *(const bf16x8*)&tb[r * 32 + ((quad ^ ((r >> 1) & 3)) << 3)];
  }
#pragma unroll
  for (int i = 0; i < 4; ++i) {
    int r = wn * 64 + i * 16 + m;
    bf[i] = *(const bf16x8*)&tb[2048 + r * 32 + ((quad ^ ((r >> 1) & 3)) << 3)];
  }
#pragma unroll
  for (int mt = 0; mt < 2; ++mt)
#pragma unroll
    for (int nt = 0; nt < 4; ++nt)
      acc[mt][nt] = MFMA16(af[mt], bf[nt], acc[mt][nt]);
}

// ---------------------------------------------------------------------------
// O projection, 64x128 tiles: 512 blocks (was 256 = 1/CU -> no cross-block
// latency hiding; now 24 KB LDS -> multiple blocks/CU).
// ---------------------------------------------------------------------------
__global__ __launch_bounds__(256) void mfma_gemm_o(const unsigned short* __restrict__ Ah,
                                                   const unsigned short* __restrict__ Wh,
                                                   const float* __restrict__ bias,
                                                   float* __restrict__ C) {
  __shared__ unsigned short ft[2][6144];       // 24 KB
  const int t = threadIdx.x, wave = t >> 6, lane = t & 63;
  const int m = lane & 15, quad = lane >> 4;
  const int wm = wave >> 1, wn = wave & 1;
  const int i0 = blockIdx.y * 64, n0 = blockIdx.x * 128;
  const int K = D_, N = D_;
  const unsigned short* Ab = Ah + (size_t)i0 * K;
  const unsigned short* Bb = Wh + (size_t)n0 * K;

  f32x4 acc[2][4] = {};

  t64_stageA(Ab, wave, lane, K, 0, &ft[0][0]);
  t64_stageB(Bb, wave, lane, K, 0, &ft[0][2048]);
  __syncthreads();

  for (int k0 = 0; k0 < K; k0 += 64) {
    t64_stageA(Ab, wave, lane, K, k0 + 32, &ft[1][0]);
    t64_stageB(Bb, wave, lane, K, k0 + 32, &ft[1][2048]);
    t64_compute(&ft[0][0], wm, wn, m, quad, acc);
    __syncthreads();
    if (k0 + 64 < K) {
      t64_stageA(Ab, wave, lane, K, k0 + 64, &ft[0][0]);
      t64_stageB(Bb, wave, lane, K, k0 + 64, &ft[0][2048]);
    }
    t64_compute(&ft[1][0], wm, wn, m, quad, acc);
    __syncthreads();
  }

  float bvv[4];
#pragma unroll
  for (int nt = 0; nt < 4; ++nt) bvv[nt] = bias[n0 + wn * 64 + nt * 16 + m];
#pragma unroll
  for (int mt = 0; mt < 2; ++mt) {
    int rbase = i0 + wm * 32 + mt * 16 + quad * 4;
#pragma unroll
    for (int nt = 0; nt < 4; ++nt) {
      int col = n0 + wn * 64 + nt * 16 + m;
#pragma unroll
      for (int r = 0; r < 4; ++r)
        C[(size_t)(rbase + r) * N + col] = acc[mt][nt][r] + bvv[nt];
    }
  }
}

// ---------------------------------------------------------------------------
// ts hierarchy, d-major layouts (coalesced against vt).
// ---------------------------------------------------------------------------
__global__ void ts8_kernel(const unsigned short* __restrict__ vt, float* __restrict__ ts8) {
  int tid = blockIdx.x * 256 + threadIdx.x;   // (b*D+d)*256 + g
  int g = tid & 255;
  int dg = tid >> 8;
  const unsigned short* p = vt + (size_t)dg * S_ + g * 8;
  ushort4 a = *(const ushort4*)p;
  ushort4 b4 = *(const ushort4*)(p + 4);
  ts8[tid] = bf2f(a.x) + bf2f(a.y) + bf2f(a.z) + bf2f(a.w) +
             bf2f(b4.x) + bf2f(b4.y) + bf2f(b4.z) + bf2f(b4.w);
}

__global__ void ts64_kernel(const float* __restrict__ ts8, float* __restrict__ ts64) {
  int tid = blockIdx.x * 256 + threadIdx.x;   // (b*D+d)*32 + T
  int T = tid & 31;
  int dg = tid >> 5;
  const float* p = ts8 + (size_t)dg * 256 + T * 8;
  float4 x = *(const float4*)p;
  float4 y = *(const float4*)(p + 4);
  ts64[tid] = x.x + x.y + x.z + x.w + y.x + y.y + y.z + y.w;
}

__global__ void tsp2_kernel(const float* __restrict__ ts64, float* __restrict__ tsp) {
  int tid = blockIdx.x * 256 + threadIdx.x;   // dg*33 + T
  int T = tid % 33;
  int dg = tid / 33;
  float s = 0.f;
  for (int u = 0; u < T; ++u) s += ts64[(size_t)dg * 32 + u];
  tsp[tid] = s;
}

// ---------------------------------------------------------------------------
// farsum GEMM: fsum[i][d] = sum_j A[i][j]*V[j][d], A from fmask bits.
// ---------------------------------------------------------------------------
__device__ __forceinline__ void fs_buildA(const ull* __restrict__ fm0, int t, int k0,
                                          unsigned short* dstA) {
  int row = t >> 2, q = t & 3;
  int cq = q ^ ((row >> 1) & 3);
  int kb = k0 + (cq << 3);
  ull w = fm0[(size_t)row * 32 + (kb >> 6)];
  unsigned byte = (unsigned)(w >> (kb & 63)) & 0xFFu;
  uint4 v;
  v.x = ((byte & 1u)   ? 0x3F80u : 0u) | ((byte & 2u)   ? 0x3F800000u : 0u);
  v.y = ((byte & 4u)   ? 0x3F80u : 0u) | ((byte & 8u)   ? 0x3F800000u : 0u);
  v.z = ((byte & 16u)  ? 0x3F80u : 0u) | ((byte & 32u)  ? 0x3F800000u : 0u);
  v.w = ((byte & 64u)  ? 0x3F80u : 0u) | ((byte & 128u) ? 0x3F800000u : 0u);
  *(uint4*)&dstA[t << 3] = v;
}

__global__ __launch_bounds__(256) void farsum_gemm(const unsigned short* __restrict__ vt,
                                                   const ull* __restrict__ fmask,
                                                   unsigned short* __restrict__ fsum) {
  __shared__ unsigned short ft[2][6144];   // [buf][A(2048) | B(4096)] = 24 KB
  const int t = threadIdx.x, wave = t >> 6, lane = t & 63;
  const int m = lane & 15, quad = lane >> 4;
  const int wm = wave >> 1, wn = wave & 1;
  const int n0 = blockIdx.x * 128;
  const int y = blockIdx.y, half = y >> 5, u = y & 31;
  const int b = u & 1;
  const int q = half ? (u >> 1) : (31 - (u >> 1));
  const int il0 = q * 64;
  const int grow0 = b * S_ + il0;
  const unsigned short* Bb = vt + ((size_t)b * D_ + n0) * S_;
  const ull* fm0 = fmask + (size_t)grow0 * 32;
  const int kend = il0;

  f32x4 acc[2][4] = {};
  if (kend > 0) {
    t64_stageB(Bb, wave, lane, S_, 0, &ft[0][2048]);
    fs_buildA(fm0, t, 0, &ft[0][0]);
    __syncthreads();
    for (int k0 = 0; k0 < kend; k0 += 64) {
      t64_stageB(Bb, wave, lane, S_, k0 + 32, &ft[1][2048]);
      fs_buildA(fm0, t, k0 + 32, &ft[1][0]);
      t64_compute(&ft[0][0], wm, wn, m, quad, acc);
      __syncthreads();
      if (k0 + 64 < kend) {
        t64_stageB(Bb, wave, lane, S_, k0 + 64, &ft[0][2048]);
        fs_buildA(fm0, t, k0 + 64, &ft[0][0]);
      }
      t64_compute(&ft[1][0], wm, wn, m, quad, acc);
      __syncthreads();
    }
  }
#pragma unroll
  for (int mt = 0; mt < 2; ++mt)
#pragma unroll
    for (int nt = 0; nt < 4; ++nt) {
      int col = n0 + wn * 64 + nt * 16 + m;
#pragma unroll
      for (int r = 0; r < 4; ++r) {
        int row = grow0 + wm * 32 + mt * 16 + quad * 4 + r;
        fsum[(size_t)row * D_ + col] = f2bf(acc[mt][nt][r]);
      }
    }
}

// ---------------------------------------------------------------------------
// Merged single-pass MFMA banded attention.
// R7 fix: K-lo correction lives ONLY in registers (bL) — R6 accidentally
// staged it to LDS too (KlP, +18.4 KB), dropping occupancy 3 -> 2 blocks/CU
// while leaving the register loads dead. LDS back to ~47.5 KB -> 3 blocks/CU.
// ---------------------------------------------------------------------------
__global__ __launch_bounds__(256, 3) void attn4_kernel(
    const unsigned short* __restrict__ qh, const unsigned short* __restrict__ ql,
    const unsigned short* __restrict__ kh, const unsigned short* __restrict__ kl,
    const unsigned short* __restrict__ vt, const unsigned short* __restrict__ farsum,
    const int* __restrict__ c0arr, const float* __restrict__ tsp,
    const ull* __restrict__ bm, const float* __restrict__ mbg,
    unsigned short* __restrict__ out) {
  const int h = blockIdx.x, i0 = blockIdx.y * 64, b = blockIdx.z;
  const int jt0 = i0 - 64;
  __shared__ unsigned short Qhs[64 * 72];
  __shared__ unsigned short Khs[128 * 72];    // reused as P[64][136]
  __shared__ unsigned short Vt[64 * 136];
  __shared__ float mrow[64], lrow[64], Mband[64];
  __shared__ float rmaxw[4][32], rsumw[4][32];
  __shared__ ull bmr[64];
  __shared__ int c0r[64];
  const int t = threadIdx.x, lane = t & 63, wave = t >> 6;
  const int m = lane & 15, quad = lane >> 4;
  const int wm = wave >> 1, wn = wave & 1;

  // register-resident lo-correction fragments (Q-lo rows, K-lo rows)
  bf16x8 aL[2][2], bL[4][2];
#pragma unroll
  for (int mt = 0; mt < 2; ++mt)
#pragma unroll
    for (int kc = 0; kc < 2; ++kc) {
      int row = i0 + wm * 32 + mt * 16 + m;
      aL[mt][kc] = *(const bf16x8*)(ql + ((size_t)(b * S_) + row) * D_ + h * 64 + kc * 32 + quad * 8);
    }
#pragma unroll
  for (int nt = 0; nt < 4; ++nt)
#pragma unroll
    for (int kc = 0; kc < 2; ++kc) {
      int jr = jt0 + wn * 64 + nt * 16 + m;
      if (jr < 0) jr = 0;                      // masked later via bmr
      bL[nt][kc] = *(const bf16x8*)(kl + ((size_t)(b * S_) + jr) * D_ + h * 64 + kc * 32 + quad * 8);
    }

  for (int c = t; c < 1024; c += 256) {
    int r = c >> 4, d4 = (c & 15) << 2;
    size_t g = ((size_t)(b * S_) + i0 + r) * D_ + h * 64 + d4;
    *(ushort4*)&Qhs[r * 72 + d4] = *(const ushort4*)(qh + g);
  }
  for (int c = t; c < 2048; c += 256) {
    int r = c >> 4, d4 = (c & 15) << 2;
    int jr = jt0 + r;
    if (jr < 0) jr = 0;
    size_t g = ((size_t)(b * S_) + jr) * D_ + h * 64 + d4;
    *(ushort4*)&Khs[r * 72 + d4] = *(const ushort4*)(kh + g);
  }
  for (int c = t; c < 2048; c += 256) {
    int d = c >> 5, j4 = (c & 31) << 2;
    int j = jt0 + j4;
    if (j < 0) j = 0;
    *(ushort4*)&Vt[d * 136 + j4] =
        *(const ushort4*)(vt + ((size_t)(b * D_) + h * 64 + d) * S_ + j);
  }
  if (t < 64) {
    Mband[t] = mbg[t];
    int grow = b * S_ + i0 + t;
    bmr[t] = bm[grow];
    int c0v = c0arr[grow];
    c0r[t] = c0v;
    mrow[t] = (c0v > 0) ? 0.f : -FLT_MAX;
  }
  __syncthreads();                              // SYNC 1

  f32x4 accS[2][4] = {};
#pragma unroll
  for (int kc = 0; kc < 2; ++kc) {
    bf16x8 aH[2], bH[4];
#pragma unroll
    for (int mt = 0; mt < 2; ++mt)
      aH[mt] = *(const bf16x8*)&Qhs[(wm * 32 + mt * 16 + m) * 72 + kc * 32 + quad * 8];
#pragma unroll
    for (int nt = 0; nt < 4; ++nt)
      bH[nt] = *(const bf16x8*)&Khs[(wn * 64 + nt * 16 + m) * 72 + kc * 32 + quad * 8];
#pragma unroll
    for (int mt = 0; mt < 2; ++mt)
#pragma unroll
      for (int nt = 0; nt < 4; ++nt) {
        accS[mt][nt] = MFMA16(aH[mt], bH[nt], accS[mt][nt]);
        accS[mt][nt] = MFMA16(aL[mt][kc], bH[nt], accS[mt][nt]);
        accS[mt][nt] = MFMA16(aH[mt], bL[nt][kc], accS[mt][nt]);
      }
  }

  float rmx[2][4];
#pragma unroll
  for (int mt = 0; mt < 2; ++mt)
#pragma unroll
    for (int r = 0; r < 4; ++r) rmx[mt][r] = -FLT_MAX;
#pragma unroll
  for (int mt = 0; mt < 2; ++mt)
#pragma unroll
    for (int nt = 0; nt < 4; ++nt)
#pragma unroll
      for (int r = 0; r < 4; ++r) {
        int il = wm * 32 + mt * 16 + quad * 4 + r;
        int jl = wn * 64 + nt * 16 + m;
        int dlt = il + 64 - jl;
        float s = -FLT_MAX;
        if (dlt >= 0 && dlt < 64 && ((bmr[il] >> dlt) & 1ull))
          s = accS[mt][nt][r] * Mband[dlt];
        accS[mt][nt][r] = s;
        rmx[mt][r] = fmaxf(rmx[mt][r], s);
      }
#pragma unroll
  for (int off = 1; off < 16; off <<= 1)
#pragma unroll
    for (int mt = 0; mt < 2; ++mt)
#pragma unroll
      for (int r = 0; r < 4; ++r)
        rmx[mt][r] = fmaxf(rmx[mt][r], __shfl_xor(rmx[mt][r], off));
  if (m == 0)
#pragma unroll
    for (int mt = 0; mt < 2; ++mt)
#pragma unroll
      for (int r = 0; r < 4; ++r)
        rmaxw[wave][mt * 16 + quad * 4 + r] = rmx[mt][r];
  __syncthreads();                              // SYNC 2
  if (t < 64) {
    int wmw = t >> 5, idx = t & 31;
    float tmax = fmaxf(rmaxw[wmw * 2][idx], rmaxw[wmw * 2 + 1][idx]);
    mrow[t] = fmaxf(mrow[t], tmax);
  }
  __syncthreads();                              // SYNC 3

  unsigned short* Pl = Khs;                     // P[64][136] (8704 <= 9216)
  float rs[2][4] = {};
#pragma unroll
  for (int mt = 0; mt < 2; ++mt)
#pragma unroll
    for (int nt = 0; nt < 4; ++nt)
#pragma unroll
      for (int r = 0; r < 4; ++r) {
        int il = wm * 32 + mt * 16 + quad * 4 + r;
        int jl = wn * 64 + nt * 16 + m;
        float s = accS[mt][nt][r];
        float p = (s > -1e37f) ? expf(s - mrow[il]) : 0.f;
        rs[mt][r] += p;
        Pl[il * 136 + jl] = f2bf(p);
      }
#pragma unroll
  for (int off = 1; off < 16; off <<= 1)
#pragma unroll
    for (int mt = 0; mt < 2; ++mt)
#pragma unroll
      for (int r = 0; r < 4; ++r)
        rs[mt][r] += __shfl_xor(rs[mt][r], off);
  if (m == 0)
#pragma unroll
    for (int mt = 0; mt < 2; ++mt)
#pragma unroll
      for (int r = 0; r < 4; ++r)
        rsumw[wave][mt * 16 + quad * 4 + r] = rs[mt][r];
  __syncthreads();                              // SYNC 4
  if (t < 64) {
    int wmw = t >> 5, idx = t & 31;
    lrow[t] = rsumw[wmw * 2][idx] + rsumw[wmw * 2 + 1][idx];
  }

  f32x4 accO[2][2] = {};
#pragma unroll
  for (int kc = 0; kc < 4; ++kc) {
    bf16x8 aP[2], bV[2];
#pragma unroll
    for (int mt = 0; mt < 2; ++mt)
      aP[mt] = *(const bf16x8*)&Pl[(wm * 32 + mt * 16 + m) * 136 + kc * 32 + quad * 8];
#pragma unroll
    for (int nt = 0; nt < 2; ++nt)
      bV[nt] = *(const bf16x8*)&Vt[(wn * 32 + nt * 16 + m) * 136 + kc * 32 + quad * 8];
#pragma unroll
    for (int mt = 0; mt < 2; ++mt)
#pragma unroll
      for (int nt = 0; nt < 2; ++nt)
        accO[mt][nt] = MFMA16(aP[mt], bV[nt], accO[mt][nt]);
  }
  __syncthreads();                              // SYNC 5

#pragma unroll
  for (int mt = 0; mt < 2; ++mt)
#pragma unroll
    for (int r = 0; r < 4; ++r) {
      int il = wm * 32 + mt * 16 + quad * 4 + r;
      int gi = i0 + il;
      float mv = mrow[il], l = lrow[il];
      int C0 = c0r[il];
      float efar = (C0 > 0) ? expf(-mv) : 0.f;
      float denom = l + (float)C0 * efar;
      bool degen = (l == 0.f && C0 == 0);
      if (degen) denom = (float)S_;
      float inv = 1.f / denom;
#pragma unroll
      for (int nt = 0; nt < 2; ++nt) {
        int d = wn * 32 + nt * 16 + m;
        size_t base = ((size_t)(b * S_) + gi) * D_ + h * 64 + d;
        float o = accO[mt][nt][r];
        if (C0 > 0) o += efar * bf2f(farsum[base]);
        if (degen) o = tsp[(size_t)(b * D_ + h * 64 + d) * 33 + 32];
        out[base] = f2bf(o * inv);
      }
    }
}

// ---------------------------------------------------------------------------
extern "C" void kernel_launch(void* const* d_in, const int* in_sizes, int n_in,
                              void* d_out, int out_size, void* d_ws, size_t ws_size,
                              hipStream_t stream) {
  const float* x     = (const float*)d_in[0];
  const float* wq    = (const float*)d_in[1];
  const float* bq    = (const float*)d_in[2];
  const float* wk    = (const float*)d_in[3];
  const float* bk    = (const float*)d_in[4];
  const float* wv    = (const float*)d_in[5];
  const float* bv    = (const float*)d_in[6];
  const float* wo    = (const float*)d_in[7];
  const float* bo    = (const float*)d_in[8];
  const float* omega = (const float*)d_in[9];
  const float* gamma = (const float*)d_in[10];
  const int*   ids   = (const int*)d_in[11];
  float* out = (float*)d_out;

  // Workspace ~77 MB (watermark: keep < 84 MB).
  char* ws = (char*)d_ws;
  const size_t SZH = (size_t)BS_ * D_ * 2;                  // 8.39 MB bf16 unit
  const size_t WH  = (size_t)D_ * D_ * 2;                   // 2.10 MB
  unsigned short* qhb = (unsigned short*)(ws);
  unsigned short* qlb = (unsigned short*)(ws + 1 * SZH);
  unsigned short* khb = (unsigned short*)(ws + 2 * SZH);
  unsigned short* klb = (unsigned short*)(ws + 3 * SZH);
  unsigned short* vtb = (unsigned short*)(ws + 4 * SZH);    // V TRANSPOSED [b][d][j]
  unsigned short* xl    = (unsigned short*)(ws + 5 * SZH);  // dies after QKV-GEMM
  unsigned short* fsumh = xl;                               // aliases xl
  unsigned short* xh    = (unsigned short*)(ws + 6 * SZH);
  unsigned short* ah    = xh;                               // attn out, after QKV-GEMM
  char* wp = ws + 7 * SZH;
  unsigned short* wqh = (unsigned short*)(wp);
  unsigned short* wql = (unsigned short*)(wp + 1 * WH);
  unsigned short* wkh = (unsigned short*)(wp + 2 * WH);
  unsigned short* wkl = (unsigned short*)(wp + 3 * WH);
  unsigned short* wvh = (unsigned short*)(wp + 4 * WH);
  unsigned short* woh = (unsigned short*)(wp + 5 * WH);
  char* tail = wp + 6 * WH;
  ull* obit = (ull*)tail;                                             // 2 MB
  float* ts8  = (float*)(tail + (size_t)V_ * 64 * 8);                 // 2.10 MB
  float* ts64 = (float*)((char*)ts8 + (size_t)B_ * 256 * D_ * 4);     // 0.26 MB
  float* tsp  = (float*)((char*)ts64 + (size_t)B_ * 32 * D_ * 4);     // 0.27 MB
  int* c0 = (int*)((char*)tsp + (size_t)B_ * 33 * D_ * 4);
  ull* bmask = (ull*)((char*)c0 + (size_t)BS_ * 4);
  float* mbg = (float*)((char*)bmask + (size_t)BS_ * 8);              // 256 B
  ull* fmask = (ull*)((char*)mbg + 256);                              // 1 MB

  prep_kernel<<<8192 + 65536 + 1, 256, 0, stream>>>(
      x, wq, wk, wv, wo, omega, gamma,
      xh, xl, wqh, wql, wkh, wkl, wvh, woh, obit, mbg);

  maskbits_kernel<<<BS_, 256, 0, stream>>>(ids, obit, fmask, c0, bmask);

  mfma_gemm_qkv<<<dim3(24, 32), 256, 0, stream>>>(xh, xl, wqh, wql, wkh, wkl, wvh,
                                                  bq, bk, bv, qhb, qlb, khb, klb, vtb);

  ts8_kernel<<<B_ * D_, 256, 0, stream>>>(vtb, ts8);
  ts64_kernel<<<(B_ * D_ * 32) / 256, 256, 0, stream>>>(ts8, ts64);
  tsp2_kernel<<<(B_ * D_ * 33) / 256, 256, 0, stream>>>(ts64, tsp);

  farsum_gemm<<<dim3(D_ / 128, 64), 256, 0, stream>>>(vtb, fmask, fsumh);

  attn4_kernel<<<dim3(H_, S_ / 64, B_), 256, 0, stream>>>(qhb, qlb, khb, klb, vtb, fsumh, c0,
                                                          tsp, bmask, mbg, ah);

  mfma_gemm_o<<<dim3(D_ / 128, BS_ / 64), 256, 0, stream>>>(ah, woh, bo, out);
}

// Round 9
// 350.271 us; speedup vs baseline: 1.0316x; 1.0316x over previous
//
#include <hip/hip_runtime.h>
#include <math.h>
#include <float.h>

#define B_ 2
#define S_ 2048
#define D_ 1024
#define H_ 16
#define V_ 4096
#define NZ_ 10
#define BS_ (B_ * S_)     // 4096 rows

typedef __attribute__((ext_vector_type(8))) __bf16 bf16x8;
typedef __attribute__((ext_vector_type(4))) float f32x4;
typedef unsigned long long ull;

#define MFMA16(a, b, c) __builtin_amdgcn_mfma_f32_16x16x32_bf16((a), (b), (c), 0, 0, 0)

__device__ __forceinline__ unsigned short f2bf(float f) {
  unsigned u = __builtin_bit_cast(unsigned, f);
  u = (u + 0x7FFFu + ((u >> 16) & 1u)) >> 16;
  return (unsigned short)u;
}
__device__ __forceinline__ float bf2f(unsigned short h) {
  unsigned u = ((unsigned)h) << 16;
  return __builtin_bit_cast(float, u);
}

// ---------------------------------------------------------------------------
// Fused prep: x hi/lo split | 4-weight split | omega bit-pack | Mband table.
// R9: omega segment re-gridded 65536 -> 4096 fat blocks x 16 independent
// load->ballot iterations (was dispatch/latency-bound: 1KB work per block).
// ---------------------------------------------------------------------------
__global__ __launch_bounds__(256) void prep_kernel(
    const float* __restrict__ x,
    const float* __restrict__ wq, const float* __restrict__ wk,
    const float* __restrict__ wv, const float* __restrict__ wo,
    const float* __restrict__ omega, const float* __restrict__ gamma,
    unsigned short* __restrict__ xh, unsigned short* __restrict__ xl,
    unsigned short* __restrict__ wqh, unsigned short* __restrict__ wql,
    unsigned short* __restrict__ wkh, unsigned short* __restrict__ wkl,
    unsigned short* __restrict__ wvh, unsigned short* __restrict__ woh,
    ull* __restrict__ obit, float* __restrict__ mbg) {
  const int bid = blockIdx.x;
  const int t = threadIdx.x;
  if (bid < 4096) {
    int i = (bid * 256 + t) * 4;
    float4 v = *(const float4*)(x + i);
    ushort4 h;
    h.x = f2bf(v.x); h.y = f2bf(v.y); h.z = f2bf(v.z); h.w = f2bf(v.w);
    *(ushort4*)(xh + i) = h;
    ushort4 l;
    l.x = f2bf(v.x - bf2f(h.x));
    l.y = f2bf(v.y - bf2f(h.y));
    l.z = f2bf(v.z - bf2f(h.z));
    l.w = f2bf(v.w - bf2f(h.w));
    *(ushort4*)(xl + i) = l;
  } else if (bid < 8192) {
    int idx = ((bid - 4096) * 256 + t) * 4;
    int w = idx >> 20;                      // D*D = 2^20
    int off = idx & ((1 << 20) - 1);
    const float* src; unsigned short* hi; unsigned short* lo;
    if (w == 0)      { src = wq; hi = wqh; lo = wql; }
    else if (w == 1) { src = wk; hi = wkh; lo = wkl; }
    else if (w == 2) { src = wv; hi = wvh; lo = nullptr; }
    else             { src = wo; hi = woh; lo = nullptr; }
    float4 v = *(const float4*)(src + off);
    ushort4 h;
    h.x = f2bf(v.x); h.y = f2bf(v.y); h.z = f2bf(v.z); h.w = f2bf(v.w);
    *(ushort4*)(hi + off) = h;
    if (lo) {
      ushort4 l;
      l.x = f2bf(v.x - bf2f(h.x));
      l.y = f2bf(v.y - bf2f(h.y));
      l.z = f2bf(v.z - bf2f(h.z));
      l.w = f2bf(v.w - bf2f(h.w));
      *(ushort4*)(lo + off) = l;
    }
  } else if (bid < 8192 + 4096) {
    // omega (V x V fp32) -> bit table obit[V][64]. bit=1: NOT masked.
    int base = (bid - 8192) * 4096;
#pragma unroll
    for (int c = 0; c < 16; ++c) {
      int e = base + c * 256 + t;
      bool ok = omega[e] != 0.f;
      ull mask = __ballot(ok);
      if ((t & 63) == 0) obit[e >> 6] = mask;
    }
  } else {
    if (t < 64) {
      float delta = (float)t;
      float ld = logf(delta + 1.f);
      float cs = 0.f;
#pragma unroll
      for (int z = 0; z < NZ_; ++z) cs += cosf(gamma[z] * ld);
      mbg[t] = expf(-delta) * cs * 0.125f;
    }
  }
}

// ---------------------------------------------------------------------------
// maskbits: fmask[row][w] bit j = 1 iff (j <= i-64) && omega-unmasked;
// c0 = popcount; bm = near-band ballot.
// ---------------------------------------------------------------------------
__global__ __launch_bounds__(256) void maskbits_kernel(const int* __restrict__ ids,
                                                       const ull* __restrict__ obit,
                                                       ull* __restrict__ fmask,
                                                       int* __restrict__ c0,
                                                       ull* __restrict__ bm) {
  const int grow = blockIdx.x;
  const int b = grow >> 11, i = grow & 2047;
  const int t = threadIdx.x, lane = t & 63, wave = t >> 6;
  const int idi = ids[grow];
  const ull* orow = obit + ((size_t)idi << 6);
  __shared__ int cnt;
  if (t == 0) cnt = 0;
  if (t < 64) {
    int jj = i - t;
    bool ok = false;
    if (jj >= 0) {
      int idj = ids[b * S_ + jj];
      ok = (orow[idj >> 6] >> (idj & 63)) & 1ull;
    }
    ull mask = __ballot(ok);
    if (t == 0) bm[grow] = mask;
  }
  __syncthreads();
  const int jmax = i - 64;
  int pc = 0;
#pragma unroll
  for (int c = 0; c < 8; ++c) {
    int j = c * 256 + t;
    bool on = false;
    if (j <= jmax) {
      int idj = ids[b * S_ + j];
      on = (orow[idj >> 6] >> (idj & 63)) & 1ull;
    }
    ull mk = __ballot(on);
    if (lane == 0) {
      fmask[(size_t)grow * 32 + c * 4 + wave] = mk;
      pc += (int)__popcll(mk);
    }
  }
  if (lane == 0 && pc) atomicAdd(&cnt, pc);
  __syncthreads();
  if (t == 0) c0[grow] = cnt;
}

// ---------------------------------------------------------------------------
// Staging helper: NT tiles of [128 rows][32 cols] bf16, XOR-swizzled k-quads.
// ---------------------------------------------------------------------------
template <int NT>
__device__ __forceinline__ void stage_tiles(const unsigned short* const* gb,
                                            int wave, int lane, int K, int k0,
                                            unsigned short* dst) {
#pragma unroll
  for (int tile = 0; tile < NT; ++tile) {
#pragma unroll
    for (int half = 0; half < 2; ++half) {
      int c = wave + half * 4;
      int s = (c << 6) + lane;
      int row = s >> 2;
      int cq = (s & 3) ^ ((s >> 3) & 3);
      const unsigned short* g = gb[tile] + (size_t)row * K + k0 + (cq << 3);
      unsigned short* l = dst + tile * 4096 + (s << 3);
      __builtin_amdgcn_global_load_lds((const __attribute__((address_space(1))) void*)g,
                                       (__attribute__((address_space(3))) void*)l,
                                       16, 0, 0);
    }
  }
}

__device__ __forceinline__ void frag_loads(const unsigned short* tb, int base, int wsel,
                                           int m, int quad, bf16x8 (&f)[4]) {
#pragma unroll
  for (int i = 0; i < 4; ++i) {
    int r = wsel * 64 + i * 16 + m;
    f[i] = *(const bf16x8*)&tb[base + r * 32 + ((quad ^ ((r >> 1) & 3)) << 3)];
  }
}

__device__ __forceinline__ void qkv_compute(const unsigned short* tb, bool split,
                                            int wm, int wn, int m, int quad,
                                            f32x4 (&acc)[4][4]) {
  bf16x8 afh[4], bfh[4];
  frag_loads(tb, 0 * 4096, wm, m, quad, afh);
  frag_loads(tb, 1 * 4096, wn, m, quad, bfh);
  if (split) {
    bf16x8 afl[4], bfl[4];
    frag_loads(tb, 2 * 4096, wm, m, quad, afl);
    frag_loads(tb, 3 * 4096, wn, m, quad, bfl);
#pragma unroll
    for (int mt = 0; mt < 4; ++mt)
#pragma unroll
      for (int nt = 0; nt < 4; ++nt) {
        acc[mt][nt] = MFMA16(afh[mt], bfh[nt], acc[mt][nt]);
        acc[mt][nt] = MFMA16(afl[mt], bfh[nt], acc[mt][nt]);
        acc[mt][nt] = MFMA16(afh[mt], bfl[nt], acc[mt][nt]);
      }
  } else {
#pragma unroll
    for (int mt = 0; mt < 4; ++mt)
#pragma unroll
      for (int nt = 0; nt < 4; ++nt)
        acc[mt][nt] = MFMA16(afh[mt], bfh[nt], acc[mt][nt]);
  }
}

// ---------------------------------------------------------------------------
// Fused Q/K/V projection GEMM; V output written TRANSPOSED via LDS.
// ---------------------------------------------------------------------------
__global__ __launch_bounds__(256) void mfma_gemm_qkv(
    const unsigned short* __restrict__ xh, const unsigned short* __restrict__ xl,
    const unsigned short* __restrict__ wqh, const unsigned short* __restrict__ wql,
    const unsigned short* __restrict__ wkh, const unsigned short* __restrict__ wkl,
    const unsigned short* __restrict__ wvh,
    const float* __restrict__ bq, const float* __restrict__ bk,
    const float* __restrict__ bv,
    unsigned short* __restrict__ qoh, unsigned short* __restrict__ qol,
    unsigned short* __restrict__ koh, unsigned short* __restrict__ kol,
    unsigned short* __restrict__ vt) {
  __shared__ unsigned short tiles[2][4 * 4096];   // 64 KB
  const int t = threadIdx.x;
  const int wave = t >> 6, lane = t & 63;
  const int which = blockIdx.x >> 3;
  const int n0 = (blockIdx.x & 7) * 128;
  const int i0 = blockIdx.y * 128;
  const int K = D_, N = D_;
  const int wm = wave >> 1, wn = wave & 1;
  const int m = lane & 15, quad = lane >> 4;

  const unsigned short* Wh = (which == 0) ? wqh : (which == 1) ? wkh : wvh;
  const unsigned short* Wl = (which == 0) ? wql : wkl;
  const float* bias = (which == 0) ? bq : (which == 1) ? bk : bv;
  unsigned short* Chi = (which == 0) ? qoh : (which == 1) ? koh : vt;
  unsigned short* Clo = (which == 0) ? qol : (which == 1) ? kol : nullptr;
  const bool split = (which < 2);

  const unsigned short* gb[4];
  gb[0] = xh + (size_t)i0 * K;
  gb[1] = Wh + (size_t)n0 * K;
  gb[2] = xl + (size_t)i0 * K;
  gb[3] = Wl + (size_t)n0 * K;

  f32x4 acc[4][4] = {};

  if (split) stage_tiles<4>(gb, wave, lane, K, 0, tiles[0]);
  else       stage_tiles<2>(gb, wave, lane, K, 0, tiles[0]);
  __syncthreads();

  for (int k0 = 0; k0 < K; k0 += 64) {
    if (split) stage_tiles<4>(gb, wave, lane, K, k0 + 32, tiles[1]);
    else       stage_tiles<2>(gb, wave, lane, K, k0 + 32, tiles[1]);
    qkv_compute(tiles[0], split, wm, wn, m, quad, acc);
    __syncthreads();
    if (k0 + 64 < K) {
      if (split) stage_tiles<4>(gb, wave, lane, K, k0 + 64, tiles[0]);
      else       stage_tiles<2>(gb, wave, lane, K, k0 + 64, tiles[0]);
    }
    qkv_compute(tiles[1], split, wm, wn, m, quad, acc);
    __syncthreads();
  }

  float bvv[4];
#pragma unroll
  for (int nt = 0; nt < 4; ++nt) bvv[nt] = bias[n0 + wn * 64 + nt * 16 + m];

  if (which == 2) {
    unsigned short* E = &tiles[0][0];           // 128 x 132 = 16896 <= 32768
#pragma unroll
    for (int mt = 0; mt < 4; ++mt)
#pragma unroll
      for (int nt = 0; nt < 4; ++nt) {
        int lc = wn * 64 + nt * 16 + m;
#pragma unroll
        for (int r = 0; r < 4; ++r) {
          int lr = wm * 64 + mt * 16 + quad * 4 + r;
          E[lr * 132 + lc] = f2bf(acc[mt][nt][r] + bvv[nt]);
        }
      }
    __syncthreads();
    const int bq2 = i0 >> 11, il0 = i0 & 2047;
    for (int c = t; c < 4096; c += 256) {
      int lcol = c >> 5, i4 = (c & 31) << 2;
      ushort4 vv;
      vv.x = E[(i4 + 0) * 132 + lcol];
      vv.y = E[(i4 + 1) * 132 + lcol];
      vv.z = E[(i4 + 2) * 132 + lcol];
      vv.w = E[(i4 + 3) * 132 + lcol];
      *(ushort4*)(Chi + ((size_t)bq2 * D_ + n0 + lcol) * S_ + il0 + i4) = vv;
    }
  } else {
#pragma unroll
    for (int mt = 0; mt < 4; ++mt) {
      int rbase = i0 + wm * 64 + mt * 16 + quad * 4;
#pragma unroll
      for (int nt = 0; nt < 4; ++nt) {
        int col = n0 + wn * 64 + nt * 16 + m;
#pragma unroll
        for (int r = 0; r < 4; ++r) {
          float val = acc[mt][nt][r] + bvv[nt];
          size_t idx = (size_t)(rbase + r) * N + col;
          unsigned short hv = f2bf(val);
          Chi[idx] = hv;
          Clo[idx] = f2bf(val - bf2f(hv));
        }
      }
    }
  }
}

// ---------------------------------------------------------------------------
// O projection, 128x128 tiles (REVERTED to R6 form: the R7/R8 64x128 retile
// raised global traffic 1.5x — 256x512KB=128MB -> 512x384KB=192MB — and its
// ~+8-10us canceled the attn4 occupancy fix).
// ---------------------------------------------------------------------------
__global__ __launch_bounds__(256) void mfma_gemm_o(const unsigned short* __restrict__ Ah,
                                                   const unsigned short* __restrict__ Wh,
                                                   const float* __restrict__ bias,
                                                   float* __restrict__ C,
                                                   int M, int N, int K) {
  __shared__ unsigned short tiles[2][2 * 4096];   // 32 KB
  const int t = threadIdx.x;
  const int wave = t >> 6, lane = t & 63;
  const int i0 = blockIdx.y * 128, n0 = blockIdx.x * 128;
  const int wm = wave >> 1, wn = wave & 1;
  const int m = lane & 15, quad = lane >> 4;

  const unsigned short* gb[2];
  gb[0] = Ah + (size_t)i0 * K;
  gb[1] = Wh + (size_t)n0 * K;

  f32x4 acc[4][4] = {};

  stage_tiles<2>(gb, wave, lane, K, 0, tiles[0]);
  __syncthreads();

  for (int k0 = 0; k0 < K; k0 += 64) {
    stage_tiles<2>(gb, wave, lane, K, k0 + 32, tiles[1]);
    qkv_compute(tiles[0], false, wm, wn, m, quad, acc);
    __syncthreads();
    if (k0 + 64 < K) stage_tiles<2>(gb, wave, lane, K, k0 + 64, tiles[0]);
    qkv_compute(tiles[1], false, wm, wn, m, quad, acc);
    __syncthreads();
  }

  float bvv[4];
#pragma unroll
  for (int nt = 0; nt < 4; ++nt) bvv[nt] = bias[n0 + wn * 64 + nt * 16 + m];
#pragma unroll
  for (int mt = 0; mt < 4; ++mt) {
    int rbase = i0 + wm * 64 + mt * 16 + quad * 4;
#pragma unroll
    for (int nt = 0; nt < 4; ++nt) {
      int col = n0 + wn * 64 + nt * 16 + m;
#pragma unroll
      for (int r = 0; r < 4; ++r)
        C[(size_t)(rbase + r) * N + col] = acc[mt][nt][r] + bvv[nt];
    }
  }
}

// ---------------------------------------------------------------------------
// vsum[b*D+d] = sum_j vt[b][d][j]. Replaces the entire ts8/ts64/tsp2 prefix
// hierarchy (dead since R6's farsum GEMM — only attn4's degen fallback needs
// the TOTAL). 32 blocks; 4 lanes per column (64B-coalesced), quad-shuffle
// reduce.
// ---------------------------------------------------------------------------
__global__ __launch_bounds__(256) void vsum_kernel(const unsigned short* __restrict__ vt,
                                                   float* __restrict__ vsum) {
  const int t = threadIdx.x;
  const int dg = blockIdx.x * 64 + (t >> 2);
  const int k = t & 3;
  const unsigned short* p = vt + (size_t)dg * S_;
  float s = 0.f;
  for (int c = 0; c < 64; ++c) {
    int j = (c * 4 + k) * 8;
    ushort4 a = *(const ushort4*)(p + j);
    ushort4 b4 = *(const ushort4*)(p + j + 4);
    s += bf2f(a.x) + bf2f(a.y) + bf2f(a.z) + bf2f(a.w) +
         bf2f(b4.x) + bf2f(b4.y) + bf2f(b4.z) + bf2f(b4.w);
  }
  s += __shfl_xor(s, 1);
  s += __shfl_xor(s, 2);
  if (k == 0) vsum[dg] = s;
}

// ---------------------------------------------------------------------------
// Shared 64x128-tile GEMM machinery (used by farsum_gemm).
// ---------------------------------------------------------------------------
__device__ __forceinline__ void t64_stageB(const unsigned short* __restrict__ Bb,
                                           int wave, int lane, int strideB, int k0,
                                           unsigned short* dstB) {
#pragma unroll
  for (int half = 0; half < 2; ++half) {
    int c = wave + half * 4;
    int s = (c << 6) + lane;
    int row = s >> 2;
    int cq = (s & 3) ^ ((s >> 3) & 3);
    const unsigned short* g = Bb + (size_t)row * strideB + k0 + (cq << 3);
    __builtin_amdgcn_global_load_lds((const __attribute__((address_space(1))) void*)g,
                                     (__attribute__((address_space(3))) void*)(dstB + (s << 3)),
                                     16, 0, 0);
  }
}

__device__ __forceinline__ void t64_compute(const unsigned short* tb,
                                            int wm, int wn, int m, int quad,
                                            f32x4 (&acc)[2][4]) {
  bf16x8 af[2], bf[4];
#pragma unroll
  for (int i = 0; i < 2; ++i) {
    int r = wm * 32 + i * 16 + m;
    af[i] = *(const bf16x8*)&tb[r * 32 + ((quad ^ ((r >> 1) & 3)) << 3)];
  }
#pragma unroll
  for (int i = 0; i < 4; ++i) {
    int r = wn * 64 + i * 16 + m;
    bf[i] = *(const bf16x8*)&tb[2048 + r * 32 + ((quad ^ ((r >> 1) & 3)) << 3)];
  }
#pragma unroll
  for (int mt = 0; mt < 2; ++mt)
#pragma unroll
    for (int nt = 0; nt < 4; ++nt)
      acc[mt][nt] = MFMA16(af[mt], bf[nt], acc[mt][nt]);
}

// ---------------------------------------------------------------------------
// farsum GEMM: fsum[i][d] = sum_j A[i][j]*V[j][d], A from fmask bits.
// ---------------------------------------------------------------------------
__device__ __forceinline__ void fs_buildA(const ull* __restrict__ fm0, int t, int k0,
                                          unsigned short* dstA) {
  int row = t >> 2, q = t & 3;
  int cq = q ^ ((row >> 1) & 3);
  int kb = k0 + (cq << 3);
  ull w = fm0[(size_t)row * 32 + (kb >> 6)];
  unsigned byte = (unsigned)(w >> (kb & 63)) & 0xFFu;
  uint4 v;
  v.x = ((byte & 1u)   ? 0x3F80u : 0u) | ((byte & 2u)   ? 0x3F800000u : 0u);
  v.y = ((byte & 4u)   ? 0x3F80u : 0u) | ((byte & 8u)   ? 0x3F800000u : 0u);
  v.z = ((byte & 16u)  ? 0x3F80u : 0u) | ((byte & 32u)  ? 0x3F800000u : 0u);
  v.w = ((byte & 64u)  ? 0x3F80u : 0u) | ((byte & 128u) ? 0x3F800000u : 0u);
  *(uint4*)&dstA[t << 3] = v;
}

__global__ __launch_bounds__(256) void farsum_gemm(const unsigned short* __restrict__ vt,
                                                   const ull* __restrict__ fmask,
                                                   unsigned short* __restrict__ fsum) {
  __shared__ unsigned short ft[2][6144];   // [buf][A(2048) | B(4096)] = 24 KB
  const int t = threadIdx.x, wave = t >> 6, lane = t & 63;
  const int m = lane & 15, quad = lane >> 4;
  const int wm = wave >> 1, wn = wave & 1;
  const int n0 = blockIdx.x * 128;
  const int y = blockIdx.y, half = y >> 5, u = y & 31;
  const int b = u & 1;
  const int q = half ? (u >> 1) : (31 - (u >> 1));
  const int il0 = q * 64;
  const int grow0 = b * S_ + il0;
  const unsigned short* Bb = vt + ((size_t)b * D_ + n0) * S_;
  const ull* fm0 = fmask + (size_t)grow0 * 32;
  const int kend = il0;

  f32x4 acc[2][4] = {};
  if (kend > 0) {
    t64_stageB(Bb, wave, lane, S_, 0, &ft[0][2048]);
    fs_buildA(fm0, t, 0, &ft[0][0]);
    __syncthreads();
    for (int k0 = 0; k0 < kend; k0 += 64) {
      t64_stageB(Bb, wave, lane, S_, k0 + 32, &ft[1][2048]);
      fs_buildA(fm0, t, k0 + 32, &ft[1][0]);
      t64_compute(&ft[0][0], wm, wn, m, quad, acc);
      __syncthreads();
      if (k0 + 64 < kend) {
        t64_stageB(Bb, wave, lane, S_, k0 + 64, &ft[0][2048]);
        fs_buildA(fm0, t, k0 + 64, &ft[0][0]);
      }
      t64_compute(&ft[1][0], wm, wn, m, quad, acc);
      __syncthreads();
    }
  }
#pragma unroll
  for (int mt = 0; mt < 2; ++mt)
#pragma unroll
    for (int nt = 0; nt < 4; ++nt) {
      int col = n0 + wn * 64 + nt * 16 + m;
#pragma unroll
      for (int r = 0; r < 4; ++r) {
        int row = grow0 + wm * 32 + mt * 16 + quad * 4 + r;
        fsum[(size_t)row * D_ + col] = f2bf(acc[mt][nt][r]);
      }
    }
}

// ---------------------------------------------------------------------------
// Merged single-pass MFMA banded attention (K-lo in registers, 3 blocks/CU).
// ---------------------------------------------------------------------------
__global__ __launch_bounds__(256, 3) void attn4_kernel(
    const unsigned short* __restrict__ qh, const unsigned short* __restrict__ ql,
    const unsigned short* __restrict__ kh, const unsigned short* __restrict__ kl,
    const unsigned short* __restrict__ vt, const unsigned short* __restrict__ farsum,
    const int* __restrict__ c0arr, const float* __restrict__ vsum,
    const ull* __restrict__ bm, const float* __restrict__ mbg,
    unsigned short* __restrict__ out) {
  const int h = blockIdx.x, i0 = blockIdx.y * 64, b = blockIdx.z;
  const int jt0 = i0 - 64;
  __shared__ unsigned short Qhs[64 * 72];
  __shared__ unsigned short Khs[128 * 72];    // reused as P[64][136]
  __shared__ unsigned short Vt[64 * 136];
  __shared__ float mrow[64], lrow[64], Mband[64];
  __shared__ float rmaxw[4][32], rsumw[4][32];
  __shared__ ull bmr[64];
  __shared__ int c0r[64];
  const int t = threadIdx.x, lane = t & 63, wave = t >> 6;
  const int m = lane & 15, quad = lane >> 4;
  const int wm = wave >> 1, wn = wave & 1;

  // register-resident lo-correction fragments (Q-lo rows, K-lo rows)
  bf16x8 aL[2][2], bL[4][2];
#pragma unroll
  for (int mt = 0; mt < 2; ++mt)
#pragma unroll
    for (int kc = 0; kc < 2; ++kc) {
      int row = i0 + wm * 32 + mt * 16 + m;
      aL[mt][kc] = *(const bf16x8*)(ql + ((size_t)(b * S_) + row) * D_ + h * 64 + kc * 32 + quad * 8);
    }
#pragma unroll
  for (int nt = 0; nt < 4; ++nt)
#pragma unroll
    for (int kc = 0; kc < 2; ++kc) {
      int jr = jt0 + wn * 64 + nt * 16 + m;
      if (jr < 0) jr = 0;                      // masked later via bmr
      bL[nt][kc] = *(const bf16x8*)(kl + ((size_t)(b * S_) + jr) * D_ + h * 64 + kc * 32 + quad * 8);
    }

  for (int c = t; c < 1024; c += 256) {
    int r = c >> 4, d4 = (c & 15) << 2;
    size_t g = ((size_t)(b * S_) + i0 + r) * D_ + h * 64 + d4;
    *(ushort4*)&Qhs[r * 72 + d4] = *(const ushort4*)(qh + g);
  }
  for (int c = t; c < 2048; c += 256) {
    int r = c >> 4, d4 = (c & 15) << 2;
    int jr = jt0 + r;
    if (jr < 0) jr = 0;
    size_t g = ((size_t)(b * S_) + jr) * D_ + h * 64 + d4;
    *(ushort4*)&Khs[r * 72 + d4] = *(const ushort4*)(kh + g);
  }
  for (int c = t; c < 2048; c += 256) {
    int d = c >> 5, j4 = (c & 31) << 2;
    int j = jt0 + j4;
    if (j < 0) j = 0;
    *(ushort4*)&Vt[d * 136 + j4] =
        *(const ushort4*)(vt + ((size_t)(b * D_) + h * 64 + d) * S_ + j);
  }
  if (t < 64) {
    Mband[t] = mbg[t];
    int grow = b * S_ + i0 + t;
    bmr[t] = bm[grow];
    int c0v = c0arr[grow];
    c0r[t] = c0v;
    mrow[t] = (c0v > 0) ? 0.f : -FLT_MAX;
  }
  __syncthreads();                              // SYNC 1

  f32x4 accS[2][4] = {};
#pragma unroll
  for (int kc = 0; kc < 2; ++kc) {
    bf16x8 aH[2], bH[4];
#pragma unroll
    for (int mt = 0; mt < 2; ++mt)
      aH[mt] = *(const bf16x8*)&Qhs[(wm * 32 + mt * 16 + m) * 72 + kc * 32 + quad * 8];
#pragma unroll
    for (int nt = 0; nt < 4; ++nt)
      bH[nt] = *(const bf16x8*)&Khs[(wn * 64 + nt * 16 + m) * 72 + kc * 32 + quad * 8];
#pragma unroll
    for (int mt = 0; mt < 2; ++mt)
#pragma unroll
      for (int nt = 0; nt < 4; ++nt) {
        accS[mt][nt] = MFMA16(aH[mt], bH[nt], accS[mt][nt]);
        accS[mt][nt] = MFMA16(aL[mt][kc], bH[nt], accS[mt][nt]);
        accS[mt][nt] = MFMA16(aH[mt], bL[nt][kc], accS[mt][nt]);
      }
  }

  float rmx[2][4];
#pragma unroll
  for (int mt = 0; mt < 2; ++mt)
#pragma unroll
    for (int r = 0; r < 4; ++r) rmx[mt][r] = -FLT_MAX;
#pragma unroll
  for (int mt = 0; mt < 2; ++mt)
#pragma unroll
    for (int nt = 0; nt < 4; ++nt)
#pragma unroll
      for (int r = 0; r < 4; ++r) {
        int il = wm * 32 + mt * 16 + quad * 4 + r;
        int jl = wn * 64 + nt * 16 + m;
        int dlt = il + 64 - jl;
        float s = -FLT_MAX;
        if (dlt >= 0 && dlt < 64 && ((bmr[il] >> dlt) & 1ull))
          s = accS[mt][nt][r] * Mband[dlt];
        accS[mt][nt][r] = s;
        rmx[mt][r] = fmaxf(rmx[mt][r], s);
      }
#pragma unroll
  for (int off = 1; off < 16; off <<= 1)
#pragma unroll
    for (int mt = 0; mt < 2; ++mt)
#pragma unroll
      for (int r = 0; r < 4; ++r)
        rmx[mt][r] = fmaxf(rmx[mt][r], __shfl_xor(rmx[mt][r], off));
  if (m == 0)
#pragma unroll
    for (int mt = 0; mt < 2; ++mt)
#pragma unroll
      for (int r = 0; r < 4; ++r)
        rmaxw[wave][mt * 16 + quad * 4 + r] = rmx[mt][r];
  __syncthreads();                              // SYNC 2
  if (t < 64) {
    int wmw = t >> 5, idx = t & 31;
    float tmax = fmaxf(rmaxw[wmw * 2][idx], rmaxw[wmw * 2 + 1][idx]);
    mrow[t] = fmaxf(mrow[t], tmax);
  }
  __syncthreads();                              // SYNC 3

  unsigned short* Pl = Khs;                     // P[64][136] (8704 <= 9216)
  float rs[2][4] = {};
#pragma unroll
  for (int mt = 0; mt < 2; ++mt)
#pragma unroll
    for (int nt = 0; nt < 4; ++nt)
#pragma unroll
      for (int r = 0; r < 4; ++r) {
        int il = wm * 32 + mt * 16 + quad * 4 + r;
        int jl = wn * 64 + nt * 16 + m;
        float s = accS[mt][nt][r];
        float p = (s > -1e37f) ? expf(s - mrow[il]) : 0.f;
        rs[mt][r] += p;
        Pl[il * 136 + jl] = f2bf(p);
      }
#pragma unroll
  for (int off = 1; off < 16; off <<= 1)
#pragma unroll
    for (int mt = 0; mt < 2; ++mt)
#pragma unroll
      for (int r = 0; r < 4; ++r)
        rs[mt][r] += __shfl_xor(rs[mt][r], off);
  if (m == 0)
#pragma unroll
    for (int mt = 0; mt < 2; ++mt)
#pragma unroll
      for (int r = 0; r < 4; ++r)
        rsumw[wave][mt * 16 + quad * 4 + r] = rs[mt][r];
  __syncthreads();                              // SYNC 4
  if (t < 64) {
    int wmw = t >> 5, idx = t & 31;
    lrow[t] = rsumw[wmw * 2][idx] + rsumw[wmw * 2 + 1][idx];
  }

  f32x4 accO[2][2] = {};
#pragma unroll
  for (int kc = 0; kc < 4; ++kc) {
    bf16x8 aP[2], bV[2];
#pragma unroll
    for (int mt = 0; mt < 2; ++mt)
      aP[mt] = *(const bf16x8*)&Pl[(wm * 32 + mt * 16 + m) * 136 + kc * 32 + quad * 8];
#pragma unroll
    for (int nt = 0; nt < 2; ++nt)
      bV[nt] = *(const bf16x8*)&Vt[(wn * 32 + nt * 16 + m) * 136 + kc * 32 + quad * 8];
#pragma unroll
    for (int mt = 0; mt < 2; ++mt)
#pragma unroll
      for (int nt = 0; nt < 2; ++nt)
        accO[mt][nt] = MFMA16(aP[mt], bV[nt], accO[mt][nt]);
  }
  __syncthreads();                              // SYNC 5

#pragma unroll
  for (int mt = 0; mt < 2; ++mt)
#pragma unroll
    for (int r = 0; r < 4; ++r) {
      int il = wm * 32 + mt * 16 + quad * 4 + r;
      int gi = i0 + il;
      float mv = mrow[il], l = lrow[il];
      int C0 = c0r[il];
      float efar = (C0 > 0) ? expf(-mv) : 0.f;
      float denom = l + (float)C0 * efar;
      bool degen = (l == 0.f && C0 == 0);
      if (degen) denom = (float)S_;
      float inv = 1.f / denom;
#pragma unroll
      for (int nt = 0; nt < 2; ++nt) {
        int d = wn * 32 + nt * 16 + m;
        size_t base = ((size_t)(b * S_) + gi) * D_ + h * 64 + d;
        float o = accO[mt][nt][r];
        if (C0 > 0) o += efar * bf2f(farsum[base]);
        if (degen) o = vsum[b * D_ + h * 64 + d];
        out[base] = f2bf(o * inv);
      }
    }
}

// ---------------------------------------------------------------------------
extern "C" void kernel_launch(void* const* d_in, const int* in_sizes, int n_in,
                              void* d_out, int out_size, void* d_ws, size_t ws_size,
                              hipStream_t stream) {
  const float* x     = (const float*)d_in[0];
  const float* wq    = (const float*)d_in[1];
  const float* bq    = (const float*)d_in[2];
  const float* wk    = (const float*)d_in[3];
  const float* bk    = (const float*)d_in[4];
  const float* wv    = (const float*)d_in[5];
  const float* bv    = (const float*)d_in[6];
  const float* wo    = (const float*)d_in[7];
  const float* bo    = (const float*)d_in[8];
  const float* omega = (const float*)d_in[9];
  const float* gamma = (const float*)d_in[10];
  const int*   ids   = (const int*)d_in[11];
  float* out = (float*)d_out;

  // Workspace ~75 MB (watermark: keep < 84 MB).
  char* ws = (char*)d_ws;
  const size_t SZH = (size_t)BS_ * D_ * 2;                  // 8.39 MB bf16 unit
  const size_t WH  = (size_t)D_ * D_ * 2;                   // 2.10 MB
  unsigned short* qhb = (unsigned short*)(ws);
  unsigned short* qlb = (unsigned short*)(ws + 1 * SZH);
  unsigned short* khb = (unsigned short*)(ws + 2 * SZH);
  unsigned short* klb = (unsigned short*)(ws + 3 * SZH);
  unsigned short* vtb = (unsigned short*)(ws + 4 * SZH);    // V TRANSPOSED [b][d][j]
  unsigned short* xl    = (unsigned short*)(ws + 5 * SZH);  // dies after QKV-GEMM
  unsigned short* fsumh = xl;                               // aliases xl
  unsigned short* xh    = (unsigned short*)(ws + 6 * SZH);
  unsigned short* ah    = xh;                               // attn out, after QKV-GEMM
  char* wp = ws + 7 * SZH;
  unsigned short* wqh = (unsigned short*)(wp);
  unsigned short* wql = (unsigned short*)(wp + 1 * WH);
  unsigned short* wkh = (unsigned short*)(wp + 2 * WH);
  unsigned short* wkl = (unsigned short*)(wp + 3 * WH);
  unsigned short* wvh = (unsigned short*)(wp + 4 * WH);
  unsigned short* woh = (unsigned short*)(wp + 5 * WH);
  char* tail = wp + 6 * WH;
  ull* obit = (ull*)tail;                                             // 2 MB
  float* vsumf = (float*)(tail + (size_t)V_ * 64 * 8);                // 8 KB
  int* c0 = (int*)((char*)vsumf + (size_t)B_ * D_ * 4);               // 16 KB
  ull* bmask = (ull*)((char*)c0 + (size_t)BS_ * 4);                   // 32 KB
  float* mbg = (float*)((char*)bmask + (size_t)BS_ * 8);              // 256 B
  ull* fmask = (ull*)((char*)mbg + 256);                              // 1 MB

  // 7 launches.
  prep_kernel<<<8192 + 4096 + 1, 256, 0, stream>>>(
      x, wq, wk, wv, wo, omega, gamma,
      xh, xl, wqh, wql, wkh, wkl, wvh, woh, obit, mbg);

  maskbits_kernel<<<BS_, 256, 0, stream>>>(ids, obit, fmask, c0, bmask);

  mfma_gemm_qkv<<<dim3(24, 32), 256, 0, stream>>>(xh, xl, wqh, wql, wkh, wkl, wvh,
                                                  bq, bk, bv, qhb, qlb, khb, klb, vtb);

  vsum_kernel<<<(B_ * D_) / 64, 256, 0, stream>>>(vtb, vsumf);

  farsum_gemm<<<dim3(D_ / 128, 64), 256, 0, stream>>>(vtb, fmask, fsumh);

  attn4_kernel<<<dim3(H_, S_ / 64, B_), 256, 0, stream>>>(qhb, qlb, khb, klb, vtb, fsumh, c0,
                                                          vsumf, bmask, mbg, ah);

  mfma_gemm_o<<<dim3(D_ / 128, BS_ / 128), 256, 0, stream>>>(ah, woh, bo, out, BS_, D_, D_);
}